// Round 1
// baseline (967.931 us; speedup 1.0000x reference)
//
#include <hip/hip_runtime.h>
#include <hip/hip_bf16.h>

// SplitModule (MoE-style split linear): out[r] = features[r] @ W[inds[r]] + b[inds[r]]
// N = 2^20 rows, D_IN = D_OUT = 128, 8 experts, fp32 in/out.
//
// Strategy: sort rows by expert (padded segments, BM-aligned) then grouped GEMM
// with fp16 split-precision MFMA (hi*hi + hi*lo + lo*hi ~ fp32 accuracy),
// A gathered into swizzled LDS, W held in registers per wave.

#define D   128
#define NE  8
#define BM  128

// ws int layout
#define WS_COUNTS  0   // 8
#define WS_CURSORS 8   // 8
#define WS_PS      16  // 9 padded segment starts
#define WS_PERM    32  // n ints

using f16x8 = __attribute__((ext_vector_type(8))) _Float16;
using f32x4 = __attribute__((ext_vector_type(4))) float;

__global__ void k_init(int* wsi) {
    if (threadIdx.x < 32) wsi[threadIdx.x] = 0;
}

__global__ void k_count(const int* __restrict__ inds, int n, int* __restrict__ counts) {
    __shared__ int h[NE];
    const int t = threadIdx.x;
    if (t < NE) h[t] = 0;
    __syncthreads();
    const int stride = gridDim.x * blockDim.x;
    for (int i = blockIdx.x * blockDim.x + t; i < n; i += stride)
        atomicAdd(&h[inds[i]], 1);
    __syncthreads();
    if (t < NE) atomicAdd(&counts[t], h[t]);
}

__global__ void k_offsets(const int* __restrict__ counts, int* __restrict__ ps) {
    if (threadIdx.x == 0 && blockIdx.x == 0) {
        int acc = 0;
        for (int e = 0; e < NE; ++e) {
            ps[e] = acc;
            acc += ((counts[e] + BM - 1) / BM) * BM;  // pad segment to BM
        }
        ps[NE] = acc;
    }
}

__global__ void k_scatter(const int* __restrict__ inds, int n,
                          int* __restrict__ cursors, const int* __restrict__ ps,
                          int* __restrict__ perm) {
    __shared__ int lcount[NE], lbase[NE], lcur[NE];
    const int t = threadIdx.x;
    if (t < NE) { lcount[t] = 0; lcur[t] = 0; }
    __syncthreads();
    const int base = blockIdx.x * 4096;
    const int end  = min(base + 4096, n);
    for (int i = base + t; i < end; i += 256)
        atomicAdd(&lcount[inds[i]], 1);
    __syncthreads();
    if (t < NE) lbase[t] = ps[t] + atomicAdd(&cursors[t], lcount[t]);
    __syncthreads();
    for (int i = base + t; i < end; i += 256) {
        const int e = inds[i];
        const int p = lbase[e] + atomicAdd(&lcur[e], 1);
        perm[p] = i;
    }
}

__device__ __forceinline__ void split16(float x, _Float16& h, _Float16& l) {
    h = (_Float16)x;
    l = (_Float16)(x - (float)h);
}

// One block = one expert-uniform tile of 128 rows x 128 cols. 256 threads (4 waves).
// Wave w computes all 128 rows x cols [w*32, w*32+32).
// A (gathered rows, f16 hi/lo) staged in XOR-swizzled LDS; W slice in registers.
__global__ __launch_bounds__(256, 2)
void k_gemm(const float* __restrict__ X, const float* __restrict__ Wp,
            const float* __restrict__ Bb, const int* __restrict__ ps,
            const int* __restrict__ counts, const int* __restrict__ perm,
            float* __restrict__ out) {
    __shared__ short Ahi[BM * D];  // f16 bits, swizzled
    __shared__ short Alo[BM * D];
    __shared__ int   perml[BM];

    const int t    = threadIdx.x;
    const int tile = blockIdx.x;
    const int total = ps[NE];
    const int base_row = tile * BM;
    if (base_row >= total) return;

    // find expert segment (tiles never span experts: segments are BM-padded)
    int e = 0;
#pragma unroll
    for (int q = 0; q < NE - 1; ++q)
        if (base_row >= ps[q + 1]) e = q + 1;
    const int nvalid = min(BM, counts[e] - (base_row - ps[e]));

    // stage perm tile
    if (t < BM) perml[t] = (t < nvalid) ? perm[base_row + t] : 0;
    __syncthreads();

    const int lane  = t & 63;
    const int wave  = t >> 6;
    const int nbase = wave * 32;

    // ---- W[e] slice -> registers, split f16 hi/lo -------------------------
    // B frag (16x16x32): lane l holds col n=l&15, k = (l>>4)*8 + j (j=0..7)
    f16x8 bhi[2][4], blo[2][4];
    {
        const size_t wb = (size_t)e * D * D;
        const int nn = nbase + (lane & 15);
#pragma unroll
        for (int nt = 0; nt < 2; ++nt) {
#pragma unroll
            for (int ks = 0; ks < 4; ++ks) {
                const int kb = ks * 32 + ((lane >> 4) << 3);
                f16x8 h, l;
#pragma unroll
                for (int j = 0; j < 8; ++j) {
                    const float x = Wp[wb + (size_t)(kb + j) * D + nn + nt * 16];
                    _Float16 hh, ll;
                    split16(x, hh, ll);
                    h[j] = hh; l[j] = ll;
                }
                bhi[nt][ks] = h; blo[nt][ks] = l;
            }
        }
    }

    // ---- A tile: gather rows, split, write swizzled LDS -------------------
    // thread t: float4 slice kq of rows m0, m0+8, ..., m0+120
    {
        const int kq = t & 31;
        const int m0 = t >> 5;
#pragma unroll
        for (int i = 0; i < 16; ++i) {
            const int m  = m0 + (i << 3);
            const int gr = perml[m];   // invalid rows -> row 0 (garbage, never stored)
            const float4 v = *reinterpret_cast<const float4*>(X + (size_t)gr * D + (kq << 2));
            union { _Float16 h[4]; short4 s; } uh, ul;
            split16(v.x, uh.h[0], ul.h[0]);
            split16(v.y, uh.h[1], ul.h[1]);
            split16(v.z, uh.h[2], ul.h[2]);
            split16(v.w, uh.h[3], ul.h[3]);
            const int eoff = (m * D + (kq << 2)) ^ ((m & 7) << 3);  // element offset, byte-XOR <<4
            *reinterpret_cast<short4*>(&Ahi[eoff]) = uh.s;
            *reinterpret_cast<short4*>(&Alo[eoff]) = ul.s;
        }
    }
    __syncthreads();

    // ---- main MFMA loop ---------------------------------------------------
    f32x4 acc[8][2];
#pragma unroll
    for (int mt = 0; mt < 8; ++mt)
#pragma unroll
        for (int nt = 0; nt < 2; ++nt)
            acc[mt][nt] = (f32x4){0.f, 0.f, 0.f, 0.f};

#pragma unroll
    for (int mt = 0; mt < 8; ++mt) {
        // A frag: lane l holds row m=l&15(+16*mt), k = (l>>4)*8 + j
        f16x8 ahi[4], alo[4];
        const int row = mt * 16 + (lane & 15);
#pragma unroll
        for (int ks = 0; ks < 4; ++ks) {
            const int eoff = (row * D + ks * 32 + ((lane >> 4) << 3)) ^ ((row & 7) << 3);
            ahi[ks] = *reinterpret_cast<const f16x8*>(&Ahi[eoff]);
            alo[ks] = *reinterpret_cast<const f16x8*>(&Alo[eoff]);
        }
#pragma unroll
        for (int nt = 0; nt < 2; ++nt) {
#pragma unroll
            for (int ks = 0; ks < 4; ++ks) {
                acc[mt][nt] = __builtin_amdgcn_mfma_f32_16x16x32_f16(ahi[ks], bhi[nt][ks], acc[mt][nt], 0, 0, 0);
                acc[mt][nt] = __builtin_amdgcn_mfma_f32_16x16x32_f16(ahi[ks], blo[nt][ks], acc[mt][nt], 0, 0, 0);
                acc[mt][nt] = __builtin_amdgcn_mfma_f32_16x16x32_f16(alo[ks], bhi[nt][ks], acc[mt][nt], 0, 0, 0);
            }
        }
    }

    // ---- epilogue: bias + scatter back ------------------------------------
    float bias[2];
#pragma unroll
    for (int nt = 0; nt < 2; ++nt)
        bias[nt] = Bb[(size_t)e * D + nbase + nt * 16 + (lane & 15)];

#pragma unroll
    for (int mt = 0; mt < 8; ++mt) {
#pragma unroll
        for (int j = 0; j < 4; ++j) {
            const int row = mt * 16 + ((lane >> 4) << 2) + j;
            if (row < nvalid) {
                const int gr = perml[row];
#pragma unroll
                for (int nt = 0; nt < 2; ++nt)
                    out[(size_t)gr * D + nbase + nt * 16 + (lane & 15)] = acc[mt][nt][j] + bias[nt];
            }
        }
    }
}

extern "C" void kernel_launch(void* const* d_in, const int* in_sizes, int n_in,
                              void* d_out, int out_size, void* d_ws, size_t ws_size,
                              hipStream_t stream) {
    const float* X    = (const float*)d_in[0];
    const int*   inds = (const int*)d_in[1];
    const float* Wp   = (const float*)d_in[2];
    const float* Bb   = (const float*)d_in[3];
    float*       out  = (float*)d_out;
    const int n = in_sizes[1];

    int* wsi = (int*)d_ws;
    int* perm = wsi + WS_PERM;

    k_init<<<1, 64, 0, stream>>>(wsi);
    k_count<<<1024, 256, 0, stream>>>(inds, n, wsi + WS_COUNTS);
    k_offsets<<<1, 1, 0, stream>>>(wsi + WS_COUNTS, wsi + WS_PS);
    k_scatter<<<(n + 4095) / 4096, 256, 0, stream>>>(inds, n, wsi + WS_CURSORS, wsi + WS_PS, perm);
    const int tiles = (n + BM - 1) / BM + NE;
    k_gemm<<<tiles, 256, 0, stream>>>(X, Wp, Bb, wsi + WS_PS, wsi + WS_COUNTS, perm, out);
}